// Round 1
// baseline (14683.208 us; speedup 1.0000x reference)
//
#include <hip/hip_runtime.h>
#include <math.h>

// ---------------------------------------------------------------------------
// Generic implicit-GEMM conv (NCHW in, OIHW weights), fp32, LDS-tiled.
//   out[b][CO_OFF+m][oh][ow] = relu( sum_{ci,kh,kw} X[b][ci][ih][iw]*W[m][ci][kh][kw] + bias[m] )
// GEMM view: A = weights [M][K] (K = CIN*KH*KW contiguous), B = im2col [K][N],
// N = BATCH*OH*OW.  Block tile: BM x BN (BM=16*TM, BN=16*TN), BK=16,
// 256 threads, each computing a TM x TN micro-tile.
// ---------------------------------------------------------------------------
template<int M_, int CIN, int KH, int KW, int H, int W, int OH, int OW,
         int STRIDE, int PAD, int BATCH, int OUTC, int CO_OFF, bool RELU,
         int TM, int TN>
__global__ __launch_bounds__(256)
void conv_gemm(const float* __restrict__ A,
               const float* __restrict__ X,
               const float* __restrict__ bias,
               float* __restrict__ out) {
  constexpr int K  = CIN * KH * KW;
  constexpr int N  = BATCH * OH * OW;
  constexpr int BK = 16;
  constexpr int BM = 16 * TM;
  constexpr int BN = 16 * TN;

  __shared__ float a_s[BK][BM];   // [k][m]
  __shared__ float b_s[BK][BN];   // [k][n]

  const int t  = threadIdx.x;
  const int tx = t & 15;
  const int ty = t >> 4;
  const int n0 = blockIdx.x * BN;
  const int m0 = blockIdx.y * BM;

  // A loader: each thread loads AQ float4s from one weight row.
  constexpr int AQ    = TM / 4;       // float4s per thread (1 or 2)
  constexpr int TPR_A = 4 / AQ;       // threads per A row (4 or 2)
  const int am = t / TPR_A;           // 0..BM-1
  const int ak = (t % TPR_A) * (4 * AQ);

  // B loader: each thread handles one k, TN consecutive n.
  constexpr int BQ = TN / 4;
  const int bk = t & 15;
  const int bn = (t >> 4) * TN;

  float acc[TM][TN];
#pragma unroll
  for (int i = 0; i < TM; i++)
#pragma unroll
    for (int j = 0; j < TN; j++) acc[i][j] = 0.f;

  for (int k0 = 0; k0 < K; k0 += BK) {
    // ---- global loads into registers ----
    float4 av[AQ];
#pragma unroll
    for (int q = 0; q < AQ; q++) {
      av[q] = make_float4(0.f, 0.f, 0.f, 0.f);
      const int kq = k0 + ak + 4 * q;
      if ((m0 + am) < M_ && kq < K)   // K % 4 == 0 for all layers -> whole quad valid
        av[q] = *reinterpret_cast<const float4*>(&A[(m0 + am) * K + kq]);
    }
    float bv[TN];
#pragma unroll
    for (int q = 0; q < TN; q++) bv[q] = 0.f;
    {
      const int kk = k0 + bk;
      if (kk < K) {
        const int ci = kk / (KH * KW);
        const int r  = kk - ci * (KH * KW);
        const int kh = r / KW;
        const int kw = r - kh * KW;
#pragma unroll
        for (int q = 0; q < TN; q++) {
          const int n = n0 + bn + q;
          if (n < N) {
            const int b   = n / (OH * OW);
            const int pos = n - b * (OH * OW);
            const int oh  = pos / OW;
            const int ow  = pos - oh * OW;
            const int ih  = oh * STRIDE - PAD + kh;
            const int iw  = ow * STRIDE - PAD + kw;
            if (ih >= 0 && ih < H && iw >= 0 && iw < W)
              bv[q] = X[((b * CIN + ci) * H + ih) * W + iw];
          }
        }
      }
    }
    __syncthreads();   // previous iteration's LDS reads done
    // ---- store to LDS ----
#pragma unroll
    for (int q = 0; q < AQ; q++) {
      const int kq = ak + 4 * q;
      a_s[kq + 0][am] = av[q].x;
      a_s[kq + 1][am] = av[q].y;
      a_s[kq + 2][am] = av[q].z;
      a_s[kq + 3][am] = av[q].w;
    }
#pragma unroll
    for (int q = 0; q < BQ; q++)
      *reinterpret_cast<float4*>(&b_s[bk][bn + 4 * q]) =
          make_float4(bv[4 * q], bv[4 * q + 1], bv[4 * q + 2], bv[4 * q + 3]);
    __syncthreads();
    // ---- compute ----
#pragma unroll
    for (int kk2 = 0; kk2 < BK; kk2++) {
      float a[TM], b[TN];
#pragma unroll
      for (int q = 0; q < AQ; q++)
        *reinterpret_cast<float4*>(&a[4 * q]) =
            *reinterpret_cast<const float4*>(&a_s[kk2][ty * TM + 4 * q]);
#pragma unroll
      for (int q = 0; q < BQ; q++)
        *reinterpret_cast<float4*>(&b[4 * q]) =
            *reinterpret_cast<const float4*>(&b_s[kk2][tx * TN + 4 * q]);
#pragma unroll
      for (int i = 0; i < TM; i++)
#pragma unroll
        for (int j = 0; j < TN; j++)
          acc[i][j] = fmaf(a[i], b[j], acc[i][j]);
    }
  }

  // ---- epilogue: bias + relu + NCHW scatter ----
#pragma unroll
  for (int i = 0; i < TM; i++) {
    const int m = m0 + ty * TM + i;
    if (m < M_) {
      const float bsv = bias[m];
#pragma unroll
      for (int j = 0; j < TN; j++) {
        const int n = n0 + tx * TN + j;
        if (n < N) {
          float v = acc[i][j] + bsv;
          if (RELU) v = fmaxf(v, 0.f);
          const int b   = n / (OH * OW);
          const int pos = n - b * (OH * OW);
          out[(b * OUTC + CO_OFF + m) * (OH * OW) + pos] = v;
        }
      }
    }
  }
}

// ---------------------------------------------------------------------------
// Fill sin buffer (256, 516, 7, 7): channels 0..3 = bb features, 260..515 =
// broadcast glob.  (Channels 4..259 are written by the obj2 conv.)
// ---------------------------------------------------------------------------
__global__ void prep_sin(const float* __restrict__ bbox,
                         const float* __restrict__ glob,
                         float* __restrict__ sinb) {
  const int b = blockIdx.x;
  const float x0 = bbox[b * 4 + 0], y0 = bbox[b * 4 + 1];
  const float x1 = bbox[b * 4 + 2], y1 = bbox[b * 4 + 3];
  const float bbv0 = x0 / 1280.f;
  const float bbv1 = y0 / 720.f;
  const float bbv2 = logf(1280.f / (x1 - x0));
  const float bbv3 = logf(720.f / (y1 - y0));
  float* base = sinb + (size_t)b * 516 * 49;
  for (int e = threadIdx.x; e < 4 * 49; e += blockDim.x) {
    const int c = e / 49;
    base[e] = (c == 0) ? bbv0 : (c == 1) ? bbv1 : (c == 2) ? bbv2 : bbv3;
  }
  for (int e = threadIdx.x; e < 256 * 49; e += blockDim.x)
    base[260 * 49 + e] = glob[e];
}

// ---------------------------------------------------------------------------
// sel3 conv (dot of 144 per object) + stable top-5 selection.
// sel2 layout: (256,16,3,3) -> 144 contiguous per object.
// ---------------------------------------------------------------------------
__global__ void score_top5(const float* __restrict__ sel2,
                           const float* __restrict__ w3,
                           const float* __restrict__ b3,
                           int* __restrict__ idx_out) {
  __shared__ float w_s[144];
  __shared__ float s_s[256];
  const int t = threadIdx.x;
  if (t < 144) w_s[t] = w3[t];
  __syncthreads();
  float acc = b3[0];
  const float* p = sel2 + t * 144;
  for (int k = 0; k < 144; k++) acc += p[k] * w_s[k];
  s_s[t] = acc;
  __syncthreads();
  if (t == 0) {
    // argsort(-s) is stable: ties -> smaller index first. Strict '>' with an
    // ascending scan reproduces that.
    for (int i = 0; i < 5; i++) {
      float best = -1e30f;
      int bi = 0;
      for (int j = 0; j < 256; j++)
        if (s_s[j] > best) { best = s_s[j]; bi = j; }
      idx_out[i] = bi;
      s_s[bi] = -1e30f;
    }
  }
}

// ---------------------------------------------------------------------------
// Pool: blocks 0..4 -> mean over 7x7 of selected objects' 260 channels, /5.
//        block 5    -> mean over 7x7 of glob (256 ch).
// ---------------------------------------------------------------------------
__global__ void pool_kernel(const float* __restrict__ sinb,
                            const float* __restrict__ glob,
                            const int* __restrict__ idx,
                            float* __restrict__ objsel,
                            float* __restrict__ g) {
  const int blk = blockIdx.x;
  const int t = threadIdx.x;
  if (blk < 5) {
    const int b = idx[blk];
    const float* base = sinb + (size_t)b * 516 * 49;
    for (int c = t; c < 260; c += blockDim.x) {
      float s = 0.f;
      for (int p = 0; p < 49; p++) s += base[c * 49 + p];
      objsel[blk * 260 + c] = s * (1.f / 245.f);   // mean(49) and /SELECT_NUM
    }
  } else {
    if (t < 256) {
      float s = 0.f;
      const float* p = glob + t * 49;
      for (int q = 0; q < 49; q++) s += p[q];
      g[t] = s * (1.f / 49.f);
    }
  }
}

// x(5,516) @ w_fc1(516,256) + b -> relu -> x1(5,256).  Cols 260..515 = g.
__global__ void fc1_kernel(const float* __restrict__ objsel,
                           const float* __restrict__ g,
                           const float* __restrict__ w,
                           const float* __restrict__ b,
                           float* __restrict__ x1) {
  const int co = threadIdx.x;   // 256
  float acc[5];
#pragma unroll
  for (int i = 0; i < 5; i++) acc[i] = b[co];
  for (int k = 0; k < 260; k++) {
    const float wv = w[k * 256 + co];
#pragma unroll
    for (int i = 0; i < 5; i++) acc[i] = fmaf(objsel[i * 260 + k], wv, acc[i]);
  }
  for (int k = 260; k < 516; k++) {
    const float wv = w[k * 256 + co];
    const float gv = g[k - 260];
#pragma unroll
    for (int i = 0; i < 5; i++) acc[i] = fmaf(gv, wv, acc[i]);
  }
#pragma unroll
  for (int i = 0; i < 5; i++) x1[i * 256 + co] = fmaxf(acc[i], 0.f);
}

// tmp(1280) @ w_fc2(1280,64)+b -> relu -> x2(64); x2 @ w_fc3(64,4)+b -> out(4)
__global__ void fc23_kernel(const float* __restrict__ x1,
                            const float* __restrict__ w2,
                            const float* __restrict__ b2,
                            const float* __restrict__ w3,
                            const float* __restrict__ b3,
                            float* __restrict__ out) {
  __shared__ float x2[64];
  const int j = threadIdx.x;   // 64
  float acc = b2[j];
  for (int k = 0; k < 1280; k++) acc = fmaf(x1[k], w2[k * 64 + j], acc);
  x2[j] = fmaxf(acc, 0.f);
  __syncthreads();
  if (j < 4) {
    float a = b3[j];
    for (int k = 0; k < 64; k++) a = fmaf(x2[k], w3[k * 4 + j], a);
    out[j] = a;
  }
}

// ---------------------------------------------------------------------------
extern "C" void kernel_launch(void* const* d_in, const int* in_sizes, int n_in,
                              void* d_out, int out_size, void* d_ws, size_t ws_size,
                              hipStream_t stream) {
  (void)in_sizes; (void)n_in; (void)out_size; (void)ws_size;
  const float* glob_feature = (const float*)d_in[0];   // (1,1024,28,28)
  const float* roi          = (const float*)d_in[1];   // (256,2048,7,7)
  const float* bbox         = (const float*)d_in[2];   // (256,4)
  const float* w_glob1      = (const float*)d_in[3];
  const float* b_glob1      = (const float*)d_in[4];
  const float* w_glob2      = (const float*)d_in[5];
  const float* b_glob2      = (const float*)d_in[6];
  const float* w_obj1       = (const float*)d_in[7];
  const float* b_obj1       = (const float*)d_in[8];
  const float* w_obj2       = (const float*)d_in[9];
  const float* b_obj2       = (const float*)d_in[10];
  const float* w_sel1       = (const float*)d_in[11];
  const float* b_sel1       = (const float*)d_in[12];
  const float* w_sel2       = (const float*)d_in[13];
  const float* b_sel2       = (const float*)d_in[14];
  const float* w_sel3       = (const float*)d_in[15];
  const float* b_sel3       = (const float*)d_in[16];
  const float* w_fc1        = (const float*)d_in[17];
  const float* b_fc1        = (const float*)d_in[18];
  const float* w_fc2        = (const float*)d_in[19];
  const float* b_fc2        = (const float*)d_in[20];
  const float* w_fc3        = (const float*)d_in[21];
  const float* b_fc3        = (const float*)d_in[22];

  float* ws = (float*)d_ws;
  // Workspace layout (floats). obj1 region is reused for the sel branch once
  // obj2 has consumed it (kernels on one stream serialize).
  float* glob1buf = ws;                                   // 512*14*14 = 100352
  float* globbuf  = ws + 100352;                          // 256*49    = 12544
  float* obj1buf  = ws + 112896;                          // 256*1024*49 = 12845056
  float* sel1buf  = obj1buf;                              // 256*256*25 = 1638400 (alias)
  float* sel2buf  = obj1buf + 1638400;                    // 256*16*9 = 36864
  int*   idxbuf   = (int*)(obj1buf + 1675264);            // 5 ints (8 slots)
  float* objsel   = obj1buf + 1675272;                    // 5*260 = 1300
  float* gbuf     = obj1buf + 1676572;                    // 256
  float* x1buf    = obj1buf + 1676828;                    // 1280
  float* sinbuf   = ws + 112896 + 12845056;               // 256*516*49 = 6472704
  // total: 19,430,656 floats = 77.7 MB

  // glob path: (1,1024,28,28) -> (1,512,14,14) -> (1,256,7,7)
  conv_gemm<512, 1024, 4, 4, 28, 28, 14, 14, 2, 1, 1, 512, 0, true, 4, 4>
      <<<dim3(4, 8), 256, 0, stream>>>(w_glob1, glob_feature, b_glob1, glob1buf);
  conv_gemm<256, 512, 4, 4, 14, 14, 7, 7, 2, 1, 1, 256, 0, true, 4, 4>
      <<<dim3(1, 4), 256, 0, stream>>>(w_glob2, glob1buf, b_glob2, globbuf);

  // sin channels 0..3 (bb) and 260..515 (glob broadcast)
  prep_sin<<<dim3(256), 256, 0, stream>>>(bbox, globbuf, sinbuf);

  // obj path: (256,2048,7,7) -> (256,1024,7,7) -> sin channels 4..259
  conv_gemm<1024, 2048, 3, 3, 7, 7, 7, 7, 1, 1, 256, 1024, 0, true, 8, 8>
      <<<dim3(98, 8), 256, 0, stream>>>(w_obj1, roi, b_obj1, obj1buf);
  conv_gemm<256, 1024, 3, 3, 7, 7, 7, 7, 1, 1, 256, 516, 4, true, 8, 8>
      <<<dim3(98, 2), 256, 0, stream>>>(w_obj2, obj1buf, b_obj2, sinbuf);

  // selection branch: (256,516,7,7) -> (256,256,5,5) -> (256,16,3,3) -> scores
  conv_gemm<256, 516, 3, 3, 7, 7, 5, 5, 1, 0, 256, 256, 0, true, 4, 4>
      <<<dim3(100, 4), 256, 0, stream>>>(w_sel1, sinbuf, b_sel1, sel1buf);
  conv_gemm<16, 256, 3, 3, 5, 5, 3, 3, 1, 0, 256, 16, 0, true, 4, 4>
      <<<dim3(36, 1), 256, 0, stream>>>(w_sel2, sel1buf, b_sel2, sel2buf);
  score_top5<<<dim3(1), 256, 0, stream>>>(sel2buf, w_sel3, b_sel3, idxbuf);

  // pooling + FC head
  pool_kernel<<<dim3(6), 256, 0, stream>>>(sinbuf, globbuf, idxbuf, objsel, gbuf);
  fc1_kernel<<<dim3(1), 256, 0, stream>>>(objsel, gbuf, w_fc1, b_fc1, x1buf);
  fc23_kernel<<<dim3(1), 64, 0, stream>>>(x1buf, w_fc2, b_fc2, w_fc3, b_fc3,
                                          (float*)d_out);
}

// Round 3
// 1554.828 us; speedup vs baseline: 9.4436x; 9.4436x over previous
//
#include <hip/hip_runtime.h>
#include <math.h>

using half8 = __attribute__((ext_vector_type(8))) _Float16;
using f32x4 = __attribute__((ext_vector_type(4))) float;

// ---------------------------------------------------------------------------
// Weight re-tiling: w (OIHW fp32) -> Wt fp16 tiles [mt][ktile][g][mi][8].
// k-tile visit order: cc (ci chunks of 128) -> khkw (9) -> sub (cw/32).
// Within tile: element (g, mi, i) = w[mt*BM+mi][cc*128+sub*32+8g+i][khkw].
// ---------------------------------------------------------------------------
template<int CIN, int KC, int M_, int BM>
__global__ void transform_w(const float* __restrict__ w, _Float16* __restrict__ wt) {
  constexpr int NT = (KC / 32) * 9;
  const size_t TOT = (size_t)(M_ / BM) * NT * BM * 32;
  size_t fid = (size_t)blockIdx.x * 256 + threadIdx.x;
  if (fid >= TOT) return;
  const int within = (int)(fid & (BM * 32 - 1));
  const int tile   = (int)(fid / (BM * 32));
  const int mt = tile / NT, kt = tile % NT;
  const int g  = within / (BM * 8);
  const int rem = within & (BM * 8 - 1);
  const int mi = rem >> 3, i = rem & 7;
  // decode kt -> (cc, khkw, sub)
  int cc = 0, ktr = kt, ns = 4;
  for (;;) {
    int cw = KC - cc * 128; if (cw > 128) cw = 128;
    int ntcc = 9 * (cw / 32);
    if (ktr < ntcc) { ns = cw / 32; break; }
    ktr -= ntcc; cc++;
  }
  const int khkw = ktr / ns, sub = ktr % ns;
  const int ci = cc * 128 + sub * 32 + 8 * g + i;
  const int m  = mt * BM + mi;
  float v = (ci < CIN) ? w[((size_t)m * CIN + ci) * 9 + khkw] : 0.f;
  wt[fid] = (_Float16)v;
}

// ---------------------------------------------------------------------------
// fp16 MFMA implicit-GEMM conv for 3x3 convs on 7x7 inputs (NCHW).
// Block: BM out-channels x 2 objects. 512 threads = 8 waves; wave (wid) does
// WM=BM/4 channels x 64 padded positions of object wid>>2.
// X patch staged per 128-ci chunk as x_s[obj][pos][ci] (row stride 136 halves
// = 272B: 16B aligned, bank-step 4 -> 2-way (free)); row 49 = zero row for
// padding/OOB. A tile staged linearly (layout matches Wt tile).
// ---------------------------------------------------------------------------
template<int KC, int M_, int BM, int FN, int OHW, int PAD, typename OUT_T, typename IN_T>
__global__ __launch_bounds__(512, 4)
void conv_mfma(const _Float16* __restrict__ Wt, const IN_T* __restrict__ X,
               const float* __restrict__ bias, OUT_T* __restrict__ out,
               int outc, int co_off) {
  constexpr int NT   = (KC / 32) * 9;
  constexpr int OPOS = OHW * OHW;
  constexpr int WM   = BM / 4;
  constexpr int FR   = WM / 16;

  __shared__ alignas(16) _Float16 a_s[BM * 32];
  __shared__ alignas(16) _Float16 x_s[2][50][136];

  const int tid  = threadIdx.x;
  const int wid  = tid >> 6;
  const int lane = tid & 63;
  const int g    = lane >> 4;
  const int ln   = lane & 15;
  const int obj  = wid >> 2;
  const int wm   = (wid & 3) * WM;
  const int mt   = blockIdx.x;
  const int op   = blockIdx.y;

  if (tid < 272) x_s[tid / 136][49][tid % 136] = (_Float16)0.f;

  int ohv[FN], owv[FN];
  bool pvv[FN];
#pragma unroll
  for (int f = 0; f < FN; f++) {
    const int pos = ln + 16 * f;
    pvv[f] = pos < OPOS;
    ohv[f] = pos / OHW;
    owv[f] = pos % OHW;
  }

  f32x4 acc[FR][FN];
#pragma unroll
  for (int r = 0; r < FR; r++)
#pragma unroll
    for (int f = 0; f < FN; f++) acc[r][f] = (f32x4){0.f, 0.f, 0.f, 0.f};

  const IN_T* X0 = X + (size_t)(2 * op) * KC * 49;
  const IN_T* X1 = X + (size_t)(2 * op + 1) * KC * 49;
  const _Float16* wtile = Wt + (size_t)mt * NT * (BM * 32);

  int ktile = 0;
  for (int cbase = 0; cbase < KC; cbase += 128) {
    const int cw = (KC - cbase < 128) ? (KC - cbase) : 128;
    __syncthreads();   // all waves done reading previous x_s chunk
    for (int e = tid; e < 2 * cw * 49; e += 512) {
      const int o = e / (cw * 49);
      const int r = e - o * (cw * 49);
      const int ci = r / 49, pos = r - ci * 49;
      const float v = (float)((o ? X1 : X0)[(size_t)cbase * 49 + r]);
      x_s[o][pos][ci] = (_Float16)v;
    }
    for (int khkw = 0; khkw < 9; khkw++) {
      const int kh = khkw / 3, kw = khkw - 3 * (khkw / 3);
      int boff[FN];
#pragma unroll
      for (int f = 0; f < FN; f++) {
        const int ih = ohv[f] + kh - PAD;
        const int iw = owv[f] + kw - PAD;
        bool v = pvv[f];
        if (PAD) v = v && ((unsigned)ih < 7u) && ((unsigned)iw < 7u);
        const int row = v ? (ih * 7 + iw) : 49;
        boff[f] = (obj * 50 * 136 + row * 136) * 2;
      }
      const int nsub = cw / 32;
      for (int sub = 0; sub < nsub; sub++) {
        __syncthreads();   // a_s reads done (and x_s staging published)
        {
          const _Float16* wt = wtile + (size_t)ktile * (BM * 32);
          // BM*32 halves total, 8 halves per half8 store -> BM*4 stores.
          for (int e = tid; e < BM * 4; e += 512)
            *(half8*)&a_s[e * 8] = *(const half8*)&wt[e * 8];
        }
        __syncthreads();
        half8 af[FR];
#pragma unroll
        for (int r = 0; r < FR; r++)
          af[r] = *(const half8*)&a_s[(g * BM + wm + r * 16 + ln) * 8];
        const char* xb = (const char*)(&x_s[0][0][0]) + (sub * 32 + 8 * g) * 2;
#pragma unroll
        for (int f = 0; f < FN; f++) {
          const half8 bf = *(const half8*)(xb + boff[f]);
#pragma unroll
          for (int r = 0; r < FR; r++)
            acc[r][f] = __builtin_amdgcn_mfma_f32_16x16x32_f16(af[r], bf, acc[r][f], 0, 0, 0);
        }
        ktile++;
      }
    }
  }

  // epilogue: D layout col=lane&15 (n), row=(lane>>4)*4+e (m within 16-frag)
  const int bo = 2 * op + obj;
#pragma unroll
  for (int f = 0; f < FN; f++) {
    const int pos = ln + 16 * f;
    if (pos < OPOS) {
#pragma unroll
      for (int r = 0; r < FR; r++) {
        const int mrow = wm + r * 16 + g * 4;
#pragma unroll
        for (int e = 0; e < 4; e++) {
          const int m = mt * BM + mrow + e;
          float v = acc[r][f][e] + bias[m];
          v = fmaxf(v, 0.f);
          out[((size_t)bo * outc + co_off + m) * OPOS + pos] = (OUT_T)v;
        }
      }
    }
  }
}

// ---------------------------------------------------------------------------
// fp32 implicit-GEMM conv + optional split-K partial output.
// ---------------------------------------------------------------------------
template<int M_, int CIN, int KH, int KW, int H, int W, int OH, int OW,
         int STRIDE, int PAD, int BATCH, int OUTC, int CO_OFF, bool RELU,
         int TM, int TN, int KSPLIT, bool PARTIAL>
__global__ __launch_bounds__(256)
void conv_gemm(const float* __restrict__ A,
               const float* __restrict__ X,
               const float* __restrict__ bias,
               float* __restrict__ out) {
  constexpr int K   = CIN * KH * KW;
  constexpr int N   = BATCH * OH * OW;
  constexpr int BK  = 16;
  constexpr int BM  = 16 * TM;
  constexpr int BN  = 16 * TN;
  constexpr int KCH = K / KSPLIT;

  __shared__ float a_s[BK][BM];
  __shared__ float b_s[BK][BN];

  const int t  = threadIdx.x;
  const int tx = t & 15;
  const int ty = t >> 4;
  const int n0 = blockIdx.x * BN;
  const int m0 = blockIdx.y * BM;
  const int kz = blockIdx.z;

  constexpr int AQ    = TM / 4;
  constexpr int TPR_A = 4 / AQ;
  const int am = t / TPR_A;
  const int ak = (t % TPR_A) * (4 * AQ);

  constexpr int BQ = TN / 4;
  const int bk = t & 15;
  const int bn = (t >> 4) * TN;

  float acc[TM][TN];
#pragma unroll
  for (int i = 0; i < TM; i++)
#pragma unroll
    for (int j = 0; j < TN; j++) acc[i][j] = 0.f;

  for (int k0 = kz * KCH; k0 < (kz + 1) * KCH; k0 += BK) {
    float4 av[AQ];
#pragma unroll
    for (int q = 0; q < AQ; q++) {
      av[q] = make_float4(0.f, 0.f, 0.f, 0.f);
      const int kq = k0 + ak + 4 * q;
      if ((m0 + am) < M_ && kq < K)
        av[q] = *reinterpret_cast<const float4*>(&A[(m0 + am) * K + kq]);
    }
    float bv[TN];
#pragma unroll
    for (int q = 0; q < TN; q++) bv[q] = 0.f;
    {
      const int kk = k0 + bk;
      if (kk < K) {
        const int ci = kk / (KH * KW);
        const int r  = kk - ci * (KH * KW);
        const int kh = r / KW;
        const int kw = r - kh * KW;
#pragma unroll
        for (int q = 0; q < TN; q++) {
          const int n = n0 + bn + q;
          if (n < N) {
            const int b   = n / (OH * OW);
            const int pos = n - b * (OH * OW);
            const int oh  = pos / OW;
            const int ow  = pos - oh * OW;
            const int ih  = oh * STRIDE - PAD + kh;
            const int iw  = ow * STRIDE - PAD + kw;
            if (ih >= 0 && ih < H && iw >= 0 && iw < W)
              bv[q] = X[((b * CIN + ci) * H + ih) * W + iw];
          }
        }
      }
    }
    __syncthreads();
#pragma unroll
    for (int q = 0; q < AQ; q++) {
      const int kq = ak + 4 * q;
      a_s[kq + 0][am] = av[q].x;
      a_s[kq + 1][am] = av[q].y;
      a_s[kq + 2][am] = av[q].z;
      a_s[kq + 3][am] = av[q].w;
    }
#pragma unroll
    for (int q = 0; q < BQ; q++)
      *reinterpret_cast<float4*>(&b_s[bk][bn + 4 * q]) =
          make_float4(bv[4 * q], bv[4 * q + 1], bv[4 * q + 2], bv[4 * q + 3]);
    __syncthreads();
#pragma unroll
    for (int kk2 = 0; kk2 < BK; kk2++) {
      float a[TM], b[TN];
#pragma unroll
      for (int q = 0; q < AQ; q++)
        *reinterpret_cast<float4*>(&a[4 * q]) =
            *reinterpret_cast<const float4*>(&a_s[kk2][ty * TM + 4 * q]);
#pragma unroll
      for (int q = 0; q < BQ; q++)
        *reinterpret_cast<float4*>(&b[4 * q]) =
            *reinterpret_cast<const float4*>(&b_s[kk2][tx * TN + 4 * q]);
#pragma unroll
      for (int i = 0; i < TM; i++)
#pragma unroll
        for (int j = 0; j < TN; j++)
          acc[i][j] = fmaf(a[i], b[j], acc[i][j]);
    }
  }

#pragma unroll
  for (int i = 0; i < TM; i++) {
    const int m = m0 + ty * TM + i;
    if (m < M_) {
#pragma unroll
      for (int j = 0; j < TN; j++) {
        const int n = n0 + tx * TN + j;
        if (n < N) {
          if (PARTIAL) {
            out[((size_t)kz * M_ + m) * N + n] = acc[i][j];
          } else {
            float v = acc[i][j] + bias[m];
            if (RELU) v = fmaxf(v, 0.f);
            const int b   = n / (OH * OW);
            const int pos = n - b * (OH * OW);
            out[(b * OUTC + CO_OFF + m) * (OH * OW) + pos] = v;
          }
        }
      }
    }
  }
}

// sum split-K partials + bias + relu
__global__ void reduce_bias_relu(const float* __restrict__ part,
                                 const float* __restrict__ bias,
                                 float* __restrict__ out, int MN, int N, int KS) {
  const int e = blockIdx.x * 256 + threadIdx.x;
  if (e >= MN) return;
  float s = 0.f;
  for (int k = 0; k < KS; k++) s += part[(size_t)k * MN + e];
  s += bias[e / N];
  out[e] = fmaxf(s, 0.f);
}

// ---------------------------------------------------------------------------
// sin buffer (256, 544, 7, 7) fp16: ch 0..3 = bb, 260..515 = glob, 516..543=0.
// (ch 4..259 written by obj2 conv.)
// ---------------------------------------------------------------------------
__global__ void prep_sin(const float* __restrict__ bbox,
                         const float* __restrict__ glob,
                         _Float16* __restrict__ sinb) {
  const int b = blockIdx.x;
  const float x0 = bbox[b * 4 + 0], y0 = bbox[b * 4 + 1];
  const float x1 = bbox[b * 4 + 2], y1 = bbox[b * 4 + 3];
  const float bbv[4] = {x0 / 1280.f, y0 / 720.f,
                        logf(1280.f / (x1 - x0)), logf(720.f / (y1 - y0))};
  _Float16* base = sinb + (size_t)b * 544 * 49;
  for (int e = threadIdx.x; e < 4 * 49; e += blockDim.x)
    base[e] = (_Float16)bbv[e / 49];
  for (int e = threadIdx.x; e < 256 * 49; e += blockDim.x)
    base[260 * 49 + e] = (_Float16)glob[e];
  for (int e = threadIdx.x; e < 28 * 49; e += blockDim.x)
    base[516 * 49 + e] = (_Float16)0.f;
}

// ---------------------------------------------------------------------------
__global__ void score_top5(const float* __restrict__ sel2,
                           const float* __restrict__ w3,
                           const float* __restrict__ b3,
                           int* __restrict__ idx_out) {
  __shared__ float w_s[144];
  __shared__ float s_s[256];
  const int t = threadIdx.x;
  if (t < 144) w_s[t] = w3[t];
  __syncthreads();
  float acc = b3[0];
  const float* p = sel2 + t * 144;
  for (int k = 0; k < 144; k++) acc += p[k] * w_s[k];
  s_s[t] = acc;
  __syncthreads();
  if (t == 0) {
    for (int i = 0; i < 5; i++) {
      float best = -1e30f;
      int bi = 0;
      for (int j = 0; j < 256; j++)
        if (s_s[j] > best) { best = s_s[j]; bi = j; }
      idx_out[i] = bi;
      s_s[bi] = -1e30f;
    }
  }
}

__global__ void pool_kernel(const _Float16* __restrict__ sinb,
                            const float* __restrict__ glob,
                            const int* __restrict__ idx,
                            float* __restrict__ objsel,
                            float* __restrict__ g) {
  const int blk = blockIdx.x;
  const int t = threadIdx.x;
  if (blk < 5) {
    const int b = idx[blk];
    const _Float16* base = sinb + (size_t)b * 544 * 49;
    for (int c = t; c < 260; c += blockDim.x) {
      float s = 0.f;
      for (int p = 0; p < 49; p++) s += (float)base[c * 49 + p];
      objsel[blk * 260 + c] = s * (1.f / 245.f);
    }
  } else {
    if (t < 256) {
      float s = 0.f;
      const float* p = glob + t * 49;
      for (int q = 0; q < 49; q++) s += p[q];
      g[t] = s * (1.f / 49.f);
    }
  }
}

__global__ void fc1_kernel(const float* __restrict__ objsel,
                           const float* __restrict__ g,
                           const float* __restrict__ w,
                           const float* __restrict__ b,
                           float* __restrict__ x1) {
  const int co = threadIdx.x;
  float acc[5];
#pragma unroll
  for (int i = 0; i < 5; i++) acc[i] = b[co];
  for (int k = 0; k < 260; k++) {
    const float wv = w[k * 256 + co];
#pragma unroll
    for (int i = 0; i < 5; i++) acc[i] = fmaf(objsel[i * 260 + k], wv, acc[i]);
  }
  for (int k = 260; k < 516; k++) {
    const float wv = w[k * 256 + co];
    const float gv = g[k - 260];
#pragma unroll
    for (int i = 0; i < 5; i++) acc[i] = fmaf(gv, wv, acc[i]);
  }
#pragma unroll
  for (int i = 0; i < 5; i++) x1[i * 256 + co] = fmaxf(acc[i], 0.f);
}

__global__ void fc23_kernel(const float* __restrict__ x1,
                            const float* __restrict__ w2,
                            const float* __restrict__ b2,
                            const float* __restrict__ w3,
                            const float* __restrict__ b3,
                            float* __restrict__ out) {
  __shared__ float x2[64];
  const int j = threadIdx.x;
  float acc = b2[j];
  for (int k = 0; k < 1280; k++) acc = fmaf(x1[k], w2[k * 64 + j], acc);
  x2[j] = fmaxf(acc, 0.f);
  __syncthreads();
  if (j < 4) {
    float a = b3[j];
    for (int k = 0; k < 64; k++) a = fmaf(x2[k], w3[k * 4 + j], a);
    out[j] = a;
  }
}

// ---------------------------------------------------------------------------
extern "C" void kernel_launch(void* const* d_in, const int* in_sizes, int n_in,
                              void* d_out, int out_size, void* d_ws, size_t ws_size,
                              hipStream_t stream) {
  (void)in_sizes; (void)n_in; (void)out_size; (void)ws_size;
  const float* glob_feature = (const float*)d_in[0];
  const float* roi          = (const float*)d_in[1];
  const float* bbox         = (const float*)d_in[2];
  const float* w_glob1      = (const float*)d_in[3];
  const float* b_glob1      = (const float*)d_in[4];
  const float* w_glob2      = (const float*)d_in[5];
  const float* b_glob2      = (const float*)d_in[6];
  const float* w_obj1       = (const float*)d_in[7];
  const float* b_obj1       = (const float*)d_in[8];
  const float* w_obj2       = (const float*)d_in[9];
  const float* b_obj2       = (const float*)d_in[10];
  const float* w_sel1       = (const float*)d_in[11];
  const float* b_sel1       = (const float*)d_in[12];
  const float* w_sel2       = (const float*)d_in[13];
  const float* b_sel2       = (const float*)d_in[14];
  const float* w_sel3       = (const float*)d_in[15];
  const float* b_sel3       = (const float*)d_in[16];
  const float* w_fc1        = (const float*)d_in[17];
  const float* b_fc1        = (const float*)d_in[18];
  const float* w_fc2        = (const float*)d_in[19];
  const float* b_fc2        = (const float*)d_in[20];
  const float* w_fc3        = (const float*)d_in[21];
  const float* b_fc3        = (const float*)d_in[22];

  float* ws = (float*)d_ws;
  // Region A (f32 [0, 9437184)): W''_obj1 during obj1; afterwards reused for
  // sinbuf / W''_obj2 / W''_sel1 / sel1buf / glob scratch (obj1 runs first).
  _Float16* wbuf1   = (_Float16*)(ws);                 // 18,874,368 halves
  _Float16* sinbuf  = (_Float16*)(ws);                 // 6,823,936 halves (alias, post-obj1)
  _Float16* wbuf2   = (_Float16*)(ws + 3412000);       // 2,359,296 halves
  _Float16* wbufs1  = (_Float16*)(ws + 4591648);       // 1,253,376 halves
  float*    sel1buf = ws + 5218336;                    // 1,638,400 f32
  float*    glob1buf= ws + 6856736;                    // 100,352 f32
  float*    part1   = ws + 6957088;                    // 802,816 f32
  float*    part2   = ws + 7759904;                    // 200,704 f32
  float*    sel2buf = ws + 7960608;                    // 36,864 f32
  _Float16* obj1buf = (_Float16*)(ws + 9437184);       // 12,845,056 halves
  float*    globbuf = ws + 15859712;                   // 12,544 f32
  int*      idxbuf  = (int*)(ws + 15872256);           // 8
  float*    objsel  = ws + 15872264;                   // 1,300
  float*    gbuf    = ws + 15873564;                   // 256
  float*    x1buf   = ws + 15873820;                   // 1,280
  // total ~63.5 MB

  // --- obj1: transform weights (into region A), then MFMA conv ---
  transform_w<2048, 2048, 1024, 256><<<dim3(73728), 256, 0, stream>>>(w_obj1, wbuf1);
  conv_mfma<2048, 1024, 256, 4, 7, 1, _Float16, float>
      <<<dim3(4, 128), 512, 0, stream>>>(wbuf1, roi, b_obj1, obj1buf, 1024, 0);

  // --- region A now free: obj2/sel1 weight transforms + glob path ---
  transform_w<1024, 1024, 256, 128><<<dim3(9216), 256, 0, stream>>>(w_obj2, wbuf2);
  transform_w<516, 544, 256, 128><<<dim3(4896), 256, 0, stream>>>(w_sel1, wbufs1);

  conv_gemm<512, 1024, 4, 4, 28, 28, 14, 14, 2, 1, 1, 512, 0, true, 4, 4, 8, true>
      <<<dim3(4, 8, 8), 256, 0, stream>>>(w_glob1, glob_feature, b_glob1, part1);
  reduce_bias_relu<<<dim3(392), 256, 0, stream>>>(part1, b_glob1, glob1buf, 100352, 196, 8);
  conv_gemm<256, 512, 4, 4, 14, 14, 7, 7, 2, 1, 1, 256, 0, true, 4, 4, 16, true>
      <<<dim3(1, 4, 16), 256, 0, stream>>>(w_glob2, glob1buf, b_glob2, part2);
  reduce_bias_relu<<<dim3(49), 256, 0, stream>>>(part2, b_glob2, globbuf, 12544, 49, 16);

  prep_sin<<<dim3(256), 256, 0, stream>>>(bbox, globbuf, sinbuf);

  // --- obj2 (writes sin ch 4..259), sel branch ---
  conv_mfma<1024, 256, 128, 4, 7, 1, _Float16, _Float16>
      <<<dim3(2, 128), 512, 0, stream>>>(wbuf2, obj1buf, b_obj2, sinbuf, 544, 4);
  conv_mfma<544, 256, 128, 2, 5, 0, float, _Float16>
      <<<dim3(2, 128), 512, 0, stream>>>(wbufs1, sinbuf, b_sel1, sel1buf, 256, 0);
  conv_gemm<16, 256, 3, 3, 5, 5, 3, 3, 1, 0, 256, 16, 0, true, 4, 4, 1, false>
      <<<dim3(36, 1, 1), 256, 0, stream>>>(w_sel2, sel1buf, b_sel2, sel2buf);
  score_top5<<<dim3(1), 256, 0, stream>>>(sel2buf, w_sel3, b_sel3, idxbuf);

  // --- pooling + FC head ---
  pool_kernel<<<dim3(6), 256, 0, stream>>>(sinbuf, globbuf, idxbuf, objsel, gbuf);
  fc1_kernel<<<dim3(1), 256, 0, stream>>>(objsel, gbuf, w_fc1, b_fc1, x1buf);
  fc23_kernel<<<dim3(1), 64, 0, stream>>>(x1buf, w_fc2, b_fc2, w_fc3, b_fc3,
                                          (float*)d_out);
}

// Round 4
// 1415.584 us; speedup vs baseline: 10.3725x; 1.0984x over previous
//
#include <hip/hip_runtime.h>
#include <math.h>

using half8 = __attribute__((ext_vector_type(8))) _Float16;
using f32x4 = __attribute__((ext_vector_type(4))) float;

// ---------------------------------------------------------------------------
// Coalesced weight re-tiling: w (OIHW fp32) -> Wt fp16 tiles
// [mt][ktile][g][mi][8].  ktile order: cc (ci chunks of 128) -> khkw (9) ->
// sub (cw/32).  Element (g,mi,i) of tile = w[mt*BM+mi][cc*128+sub*32+8g+i][khkw].
// Block = 32 m-rows x 32 ci x 9 khkw staged through LDS: reads are contiguous
// 288-float row chunks, writes are contiguous 16B-granular chunks.
// ---------------------------------------------------------------------------
template<int CIN, int KC, int M_, int BM>
__global__ __launch_bounds__(256)
void transform_w(const float* __restrict__ w, _Float16* __restrict__ wt) {
  constexpr int NT = (KC / 32) * 9;
  __shared__ float lds[32 * 289];
  const int tid = threadIdx.x;
  const int s   = blockIdx.x;          // ci chunk of 32: ci0 = 32*s
  const int m0  = blockIdx.y * 32;
  const int ci0 = s * 32;
  int vlen = (CIN - ci0) * 9;          // valid floats per row chunk
  if (vlen > 288) vlen = 288;
  if (vlen < 0) vlen = 0;

  for (int e = tid; e < 32 * 288; e += 256) {
    const int mi = e / 288, o = e - mi * 288;
    float v = 0.f;
    if (o < vlen) v = w[(size_t)(m0 + mi) * (CIN * 9) + (size_t)ci0 * 9 + o];
    lds[mi * 289 + o] = v;
  }
  __syncthreads();

  const int cc  = s >> 2;
  const int sub = s & 3;
  int ns = (KC - 128 * cc) / 32; if (ns > 4) ns = 4;
  const int mt = m0 / BM;
  const int mb = m0 - mt * BM;         // m offset within BM tile
  _Float16* base = wt + (size_t)mt * NT * (BM * 32);

  for (int u = tid; u < 36 * 256; u += 256) {
    const int chunk  = u >> 8;         // 0..35
    const int within = u & 255;
    const int g = chunk & 3, khkw = chunk >> 2;
    const int mi = within >> 3, i = within & 7;
    const int kt = 36 * cc + khkw * ns + sub;
    const float v = lds[mi * 289 + (8 * g + i) * 9 + khkw];
    base[(size_t)kt * (BM * 32) + g * (BM * 8) + (mb + mi) * 8 + i] = (_Float16)v;
  }
}

// ---------------------------------------------------------------------------
// fp16 MFMA implicit-GEMM conv for 3x3 convs on 7x7 inputs (NCHW).
// Block: BM out-channels x 2 objects, 512 threads = 8 waves = 4 m-groups x 2
// objects.  A-fragments (weights) are read DIRECTLY from global Wt (L1/L2
// resident; contiguous 16B per lane by construction) -- no a_s LDS tile, no
// per-ktile barriers.  Only X is staged in LDS (per 128-ci chunk, 2 barriers
// per chunk).  Row 49 of x_s = zero row for padding/OOB.
// ---------------------------------------------------------------------------
template<int KC, int M_, int BM, int FN, int OHW, int PAD, typename OUT_T, typename IN_T>
__global__ __launch_bounds__(512, 4)
void conv_mfma(const _Float16* __restrict__ Wt, const IN_T* __restrict__ X,
               const float* __restrict__ bias, OUT_T* __restrict__ out,
               int outc, int co_off) {
  constexpr int NT   = (KC / 32) * 9;
  constexpr int OPOS = OHW * OHW;
  constexpr int WM   = BM / 4;
  constexpr int FR   = WM / 16;

  __shared__ alignas(16) _Float16 x_s[2][50][136];

  const int tid  = threadIdx.x;
  const int wid  = tid >> 6;
  const int lane = tid & 63;
  const int g    = lane >> 4;
  const int ln   = lane & 15;
  const int obj  = wid >> 3 ? 1 : (wid >> 2);   // wid in 0..7 -> obj = wid>>2
  const int wm   = (wid & 3) * WM;
  const int mt   = blockIdx.x;
  const int op   = blockIdx.y;

  if (tid < 272) x_s[tid / 136][49][tid % 136] = (_Float16)0.f;

  int ohv[FN], owv[FN];
  bool pvv[FN];
#pragma unroll
  for (int f = 0; f < FN; f++) {
    const int pos = ln + 16 * f;
    pvv[f] = pos < OPOS;
    ohv[f] = pos / OHW;
    owv[f] = pos % OHW;
  }

  f32x4 acc[FR][FN];
#pragma unroll
  for (int r = 0; r < FR; r++)
#pragma unroll
    for (int f = 0; f < FN; f++) acc[r][f] = (f32x4){0.f, 0.f, 0.f, 0.f};

  const IN_T* X0 = X + (size_t)(2 * op) * KC * 49;
  const IN_T* X1 = X + (size_t)(2 * op + 1) * KC * 49;
  const _Float16* wtile = Wt + (size_t)mt * NT * (BM * 32);
  const int afoff = (g * BM + wm + ln) * 8;   // halves within a ktile block

  int ktile = 0;
  for (int cbase = 0; cbase < KC; cbase += 128) {
    const int cw = (KC - cbase < 128) ? (KC - cbase) : 128;
    __syncthreads();   // all waves done reading previous x_s chunk
    for (int e = tid; e < 2 * cw * 49; e += 512) {
      const int o = e / (cw * 49);
      const int r = e - o * (cw * 49);
      const int ci = r / 49, pos = r - ci * 49;
      const float v = (float)((o ? X1 : X0)[(size_t)cbase * 49 + r]);
      x_s[o][pos][ci] = (_Float16)v;
    }
    __syncthreads();
    const int nsub = cw / 32;
    for (int khkw = 0; khkw < 9; khkw++) {
      const int kh = khkw / 3, kw = khkw - 3 * (khkw / 3);
      int boff[FN];
#pragma unroll
      for (int f = 0; f < FN; f++) {
        const int ih = ohv[f] + kh - PAD;
        const int iw = owv[f] + kw - PAD;
        bool v = pvv[f];
        if (PAD) v = v && ((unsigned)ih < 7u) && ((unsigned)iw < 7u);
        const int row = v ? (ih * 7 + iw) : 49;
        boff[f] = (obj * 50 * 136 + row * 136) * 2;
      }
      for (int sub = 0; sub < nsub; sub++) {
        const _Float16* ap = wtile + (size_t)ktile * (BM * 32) + afoff;
        half8 af[FR];
#pragma unroll
        for (int r = 0; r < FR; r++)
          af[r] = *(const half8*)(ap + r * 128);   // +r*16 rows * 8 halves
        const char* xb = (const char*)(&x_s[0][0][0]) + (sub * 32 + 8 * g) * 2;
#pragma unroll
        for (int f = 0; f < FN; f++) {
          const half8 bf = *(const half8*)(xb + boff[f]);
#pragma unroll
          for (int r = 0; r < FR; r++)
            acc[r][f] = __builtin_amdgcn_mfma_f32_16x16x32_f16(af[r], bf, acc[r][f], 0, 0, 0);
        }
        ktile++;
      }
    }
  }

  // epilogue: D layout col=lane&15 (n), row=(lane>>4)*4+e (m within 16-frag)
  const int bo = 2 * op + obj;
#pragma unroll
  for (int f = 0; f < FN; f++) {
    const int pos = ln + 16 * f;
    if (pos < OPOS) {
#pragma unroll
      for (int r = 0; r < FR; r++) {
        const int mrow = wm + r * 16 + g * 4;
#pragma unroll
        for (int e = 0; e < 4; e++) {
          const int m = mt * BM + mrow + e;
          float v = acc[r][f][e] + bias[m];
          v = fmaxf(v, 0.f);
          out[((size_t)bo * outc + co_off + m) * OPOS + pos] = (OUT_T)v;
        }
      }
    }
  }
}

// ---------------------------------------------------------------------------
// fp32 implicit-GEMM conv + optional split-K partial output.
// ---------------------------------------------------------------------------
template<int M_, int CIN, int KH, int KW, int H, int W, int OH, int OW,
         int STRIDE, int PAD, int BATCH, int OUTC, int CO_OFF, bool RELU,
         int TM, int TN, int KSPLIT, bool PARTIAL>
__global__ __launch_bounds__(256)
void conv_gemm(const float* __restrict__ A,
               const float* __restrict__ X,
               const float* __restrict__ bias,
               float* __restrict__ out) {
  constexpr int K   = CIN * KH * KW;
  constexpr int N   = BATCH * OH * OW;
  constexpr int BK  = 16;
  constexpr int BM  = 16 * TM;
  constexpr int BN  = 16 * TN;
  constexpr int KCH = K / KSPLIT;

  __shared__ float a_s[BK][BM];
  __shared__ float b_s[BK][BN];

  const int t  = threadIdx.x;
  const int tx = t & 15;
  const int ty = t >> 4;
  const int n0 = blockIdx.x * BN;
  const int m0 = blockIdx.y * BM;
  const int kz = blockIdx.z;

  constexpr int AQ    = TM / 4;
  constexpr int TPR_A = 4 / AQ;
  const int am = t / TPR_A;
  const int ak = (t % TPR_A) * (4 * AQ);

  constexpr int BQ = TN / 4;
  const int bk = t & 15;
  const int bn = (t >> 4) * TN;

  float acc[TM][TN];
#pragma unroll
  for (int i = 0; i < TM; i++)
#pragma unroll
    for (int j = 0; j < TN; j++) acc[i][j] = 0.f;

  for (int k0 = kz * KCH; k0 < (kz + 1) * KCH; k0 += BK) {
    float4 av[AQ];
#pragma unroll
    for (int q = 0; q < AQ; q++) {
      av[q] = make_float4(0.f, 0.f, 0.f, 0.f);
      const int kq = k0 + ak + 4 * q;
      if ((m0 + am) < M_ && kq < K)
        av[q] = *reinterpret_cast<const float4*>(&A[(m0 + am) * K + kq]);
    }
    float bv[TN];
#pragma unroll
    for (int q = 0; q < TN; q++) bv[q] = 0.f;
    {
      const int kk = k0 + bk;
      if (kk < K) {
        const int ci = kk / (KH * KW);
        const int r  = kk - ci * (KH * KW);
        const int kh = r / KW;
        const int kw = r - kh * KW;
#pragma unroll
        for (int q = 0; q < TN; q++) {
          const int n = n0 + bn + q;
          if (n < N) {
            const int b   = n / (OH * OW);
            const int pos = n - b * (OH * OW);
            const int oh  = pos / OW;
            const int ow  = pos - oh * OW;
            const int ih  = oh * STRIDE - PAD + kh;
            const int iw  = ow * STRIDE - PAD + kw;
            if (ih >= 0 && ih < H && iw >= 0 && iw < W)
              bv[q] = X[((b * CIN + ci) * H + ih) * W + iw];
          }
        }
      }
    }
    __syncthreads();
#pragma unroll
    for (int q = 0; q < AQ; q++) {
      const int kq = ak + 4 * q;
      a_s[kq + 0][am] = av[q].x;
      a_s[kq + 1][am] = av[q].y;
      a_s[kq + 2][am] = av[q].z;
      a_s[kq + 3][am] = av[q].w;
    }
#pragma unroll
    for (int q = 0; q < BQ; q++)
      *reinterpret_cast<float4*>(&b_s[bk][bn + 4 * q]) =
          make_float4(bv[4 * q], bv[4 * q + 1], bv[4 * q + 2], bv[4 * q + 3]);
    __syncthreads();
#pragma unroll
    for (int kk2 = 0; kk2 < BK; kk2++) {
      float a[TM], b[TN];
#pragma unroll
      for (int q = 0; q < AQ; q++)
        *reinterpret_cast<float4*>(&a[4 * q]) =
            *reinterpret_cast<const float4*>(&a_s[kk2][ty * TM + 4 * q]);
#pragma unroll
      for (int q = 0; q < BQ; q++)
        *reinterpret_cast<float4*>(&b[4 * q]) =
            *reinterpret_cast<const float4*>(&b_s[kk2][tx * TN + 4 * q]);
#pragma unroll
      for (int i = 0; i < TM; i++)
#pragma unroll
        for (int j = 0; j < TN; j++)
          acc[i][j] = fmaf(a[i], b[j], acc[i][j]);
    }
  }

#pragma unroll
  for (int i = 0; i < TM; i++) {
    const int m = m0 + ty * TM + i;
    if (m < M_) {
#pragma unroll
      for (int j = 0; j < TN; j++) {
        const int n = n0 + tx * TN + j;
        if (n < N) {
          if (PARTIAL) {
            out[((size_t)kz * M_ + m) * N + n] = acc[i][j];
          } else {
            float v = acc[i][j] + bias[m];
            if (RELU) v = fmaxf(v, 0.f);
            const int b   = n / (OH * OW);
            const int pos = n - b * (OH * OW);
            out[(b * OUTC + CO_OFF + m) * (OH * OW) + pos] = v;
          }
        }
      }
    }
  }
}

// sum split-K partials + bias + relu
__global__ void reduce_bias_relu(const float* __restrict__ part,
                                 const float* __restrict__ bias,
                                 float* __restrict__ out, int MN, int N, int KS) {
  const int e = blockIdx.x * 256 + threadIdx.x;
  if (e >= MN) return;
  float s = 0.f;
  for (int k = 0; k < KS; k++) s += part[(size_t)k * MN + e];
  s += bias[e / N];
  out[e] = fmaxf(s, 0.f);
}

// ---------------------------------------------------------------------------
// sin buffer (256, 544, 7, 7) fp16: ch 0..3 = bb, 260..515 = glob, 516..543=0.
// (ch 4..259 written by obj2 conv.)
// ---------------------------------------------------------------------------
__global__ void prep_sin(const float* __restrict__ bbox,
                         const float* __restrict__ glob,
                         _Float16* __restrict__ sinb) {
  const int b = blockIdx.x;
  const float x0 = bbox[b * 4 + 0], y0 = bbox[b * 4 + 1];
  const float x1 = bbox[b * 4 + 2], y1 = bbox[b * 4 + 3];
  const float bbv[4] = {x0 / 1280.f, y0 / 720.f,
                        logf(1280.f / (x1 - x0)), logf(720.f / (y1 - y0))};
  _Float16* base = sinb + (size_t)b * 544 * 49;
  for (int e = threadIdx.x; e < 4 * 49; e += blockDim.x)
    base[e] = (_Float16)bbv[e / 49];
  for (int e = threadIdx.x; e < 256 * 49; e += blockDim.x)
    base[260 * 49 + e] = (_Float16)glob[e];
  for (int e = threadIdx.x; e < 28 * 49; e += blockDim.x)
    base[516 * 49 + e] = (_Float16)0.f;
}

// ---------------------------------------------------------------------------
__global__ void score_top5(const float* __restrict__ sel2,
                           const float* __restrict__ w3,
                           const float* __restrict__ b3,
                           int* __restrict__ idx_out) {
  __shared__ float w_s[144];
  __shared__ float s_s[256];
  const int t = threadIdx.x;
  if (t < 144) w_s[t] = w3[t];
  __syncthreads();
  float acc = b3[0];
  const float* p = sel2 + t * 144;
  for (int k = 0; k < 144; k++) acc += p[k] * w_s[k];
  s_s[t] = acc;
  __syncthreads();
  if (t == 0) {
    for (int i = 0; i < 5; i++) {
      float best = -1e30f;
      int bi = 0;
      for (int j = 0; j < 256; j++)
        if (s_s[j] > best) { best = s_s[j]; bi = j; }
      idx_out[i] = bi;
      s_s[bi] = -1e30f;
    }
  }
}

__global__ void pool_kernel(const _Float16* __restrict__ sinb,
                            const float* __restrict__ glob,
                            const int* __restrict__ idx,
                            float* __restrict__ objsel,
                            float* __restrict__ g) {
  const int blk = blockIdx.x;
  const int t = threadIdx.x;
  if (blk < 5) {
    const int b = idx[blk];
    const _Float16* base = sinb + (size_t)b * 544 * 49;
    for (int c = t; c < 260; c += blockDim.x) {
      float s = 0.f;
      for (int p = 0; p < 49; p++) s += (float)base[c * 49 + p];
      objsel[blk * 260 + c] = s * (1.f / 245.f);
    }
  } else {
    if (t < 256) {
      float s = 0.f;
      const float* p = glob + t * 49;
      for (int q = 0; q < 49; q++) s += p[q];
      g[t] = s * (1.f / 49.f);
    }
  }
}

__global__ void fc1_kernel(const float* __restrict__ objsel,
                           const float* __restrict__ g,
                           const float* __restrict__ w,
                           const float* __restrict__ b,
                           float* __restrict__ x1) {
  const int co = threadIdx.x;
  float acc[5];
#pragma unroll
  for (int i = 0; i < 5; i++) acc[i] = b[co];
  for (int k = 0; k < 260; k++) {
    const float wv = w[k * 256 + co];
#pragma unroll
    for (int i = 0; i < 5; i++) acc[i] = fmaf(objsel[i * 260 + k], wv, acc[i]);
  }
  for (int k = 260; k < 516; k++) {
    const float wv = w[k * 256 + co];
    const float gv = g[k - 260];
#pragma unroll
    for (int i = 0; i < 5; i++) acc[i] = fmaf(gv, wv, acc[i]);
  }
#pragma unroll
  for (int i = 0; i < 5; i++) x1[i * 256 + co] = fmaxf(acc[i], 0.f);
}

__global__ void fc23_kernel(const float* __restrict__ x1,
                            const float* __restrict__ w2,
                            const float* __restrict__ b2,
                            const float* __restrict__ w3,
                            const float* __restrict__ b3,
                            float* __restrict__ out) {
  __shared__ float x2[64];
  const int j = threadIdx.x;
  float acc = b2[j];
  for (int k = 0; k < 1280; k++) acc = fmaf(x1[k], w2[k * 64 + j], acc);
  x2[j] = fmaxf(acc, 0.f);
  __syncthreads();
  if (j < 4) {
    float a = b3[j];
    for (int k = 0; k < 64; k++) a = fmaf(x2[k], w3[k * 4 + j], a);
    out[j] = a;
  }
}

// ---------------------------------------------------------------------------
extern "C" void kernel_launch(void* const* d_in, const int* in_sizes, int n_in,
                              void* d_out, int out_size, void* d_ws, size_t ws_size,
                              hipStream_t stream) {
  (void)in_sizes; (void)n_in; (void)out_size; (void)ws_size;
  const float* glob_feature = (const float*)d_in[0];
  const float* roi          = (const float*)d_in[1];
  const float* bbox         = (const float*)d_in[2];
  const float* w_glob1      = (const float*)d_in[3];
  const float* b_glob1      = (const float*)d_in[4];
  const float* w_glob2      = (const float*)d_in[5];
  const float* b_glob2      = (const float*)d_in[6];
  const float* w_obj1       = (const float*)d_in[7];
  const float* b_obj1       = (const float*)d_in[8];
  const float* w_obj2       = (const float*)d_in[9];
  const float* b_obj2       = (const float*)d_in[10];
  const float* w_sel1       = (const float*)d_in[11];
  const float* b_sel1       = (const float*)d_in[12];
  const float* w_sel2       = (const float*)d_in[13];
  const float* b_sel2       = (const float*)d_in[14];
  const float* w_sel3       = (const float*)d_in[15];
  const float* b_sel3       = (const float*)d_in[16];
  const float* w_fc1        = (const float*)d_in[17];
  const float* b_fc1        = (const float*)d_in[18];
  const float* w_fc2        = (const float*)d_in[19];
  const float* b_fc2        = (const float*)d_in[20];
  const float* w_fc3        = (const float*)d_in[21];
  const float* b_fc3        = (const float*)d_in[22];

  float* ws = (float*)d_ws;
  // Region A (f32 [0, 9437184)): W''_obj1 during obj1; afterwards reused for
  // sinbuf / W''_obj2 / W''_sel1 / sel1buf / glob scratch (obj1 runs first).
  _Float16* wbuf1   = (_Float16*)(ws);                 // 18,874,368 halves
  _Float16* sinbuf  = (_Float16*)(ws);                 // 6,823,936 halves (alias, post-obj1)
  _Float16* wbuf2   = (_Float16*)(ws + 3412000);       // 2,359,296 halves
  _Float16* wbufs1  = (_Float16*)(ws + 4591648);       // 1,253,376 halves
  float*    sel1buf = ws + 5218336;                    // 1,638,400 f32
  float*    glob1buf= ws + 6856736;                    // 100,352 f32
  float*    part1   = ws + 6957088;                    // 1,605,632 f32 (16-way)
  float*    part2   = ws + 8562720;                    // 200,704 f32
  float*    sel2buf = ws + 8763424;                    // 36,864 f32
  _Float16* obj1buf = (_Float16*)(ws + 9437184);       // 12,845,056 halves
  float*    globbuf = ws + 15859712;                   // 12,544 f32
  int*      idxbuf  = (int*)(ws + 15872256);           // 8
  float*    objsel  = ws + 15872264;                   // 1,300
  float*    gbuf    = ws + 15873564;                   // 256
  float*    x1buf   = ws + 15873820;                   // 1,280
  // total ~63.5 MB

  // --- obj1: transform weights (into region A), then MFMA conv ---
  transform_w<2048, 2048, 1024, 256><<<dim3(64, 32), 256, 0, stream>>>(w_obj1, wbuf1);
  conv_mfma<2048, 1024, 256, 4, 7, 1, _Float16, float>
      <<<dim3(4, 128), 512, 0, stream>>>(wbuf1, roi, b_obj1, obj1buf, 1024, 0);

  // --- region A now free: obj2/sel1 weight transforms + glob path ---
  transform_w<1024, 1024, 256, 128><<<dim3(32, 8), 256, 0, stream>>>(w_obj2, wbuf2);
  transform_w<516, 544, 256, 128><<<dim3(17, 8), 256, 0, stream>>>(w_sel1, wbufs1);

  conv_gemm<512, 1024, 4, 4, 28, 28, 14, 14, 2, 1, 1, 512, 0, true, 4, 4, 16, true>
      <<<dim3(4, 8, 16), 256, 0, stream>>>(w_glob1, glob_feature, b_glob1, part1);
  reduce_bias_relu<<<dim3(392), 256, 0, stream>>>(part1, b_glob1, glob1buf, 100352, 196, 16);
  conv_gemm<256, 512, 4, 4, 14, 14, 7, 7, 2, 1, 1, 256, 0, true, 4, 4, 16, true>
      <<<dim3(1, 4, 16), 256, 0, stream>>>(w_glob2, glob1buf, b_glob2, part2);
  reduce_bias_relu<<<dim3(49), 256, 0, stream>>>(part2, b_glob2, globbuf, 12544, 49, 16);

  prep_sin<<<dim3(256), 256, 0, stream>>>(bbox, globbuf, sinbuf);

  // --- obj2 (writes sin ch 4..259), sel branch ---
  conv_mfma<1024, 256, 128, 4, 7, 1, _Float16, _Float16>
      <<<dim3(2, 128), 512, 0, stream>>>(wbuf2, obj1buf, b_obj2, sinbuf, 544, 4);
  conv_mfma<544, 256, 128, 2, 5, 0, float, _Float16>
      <<<dim3(2, 128), 512, 0, stream>>>(wbufs1, sinbuf, b_sel1, sel1buf, 256, 0);
  conv_gemm<16, 256, 3, 3, 5, 5, 3, 3, 1, 0, 256, 16, 0, true, 4, 4, 1, false>
      <<<dim3(36, 1, 1), 256, 0, stream>>>(w_sel2, sel1buf, b_sel2, sel2buf);
  score_top5<<<dim3(1), 256, 0, stream>>>(sel2buf, w_sel3, b_sel3, idxbuf);

  // --- pooling + FC head ---
  pool_kernel<<<dim3(6), 256, 0, stream>>>(sinbuf, globbuf, idxbuf, objsel, gbuf);
  fc1_kernel<<<dim3(1), 256, 0, stream>>>(objsel, gbuf, w_fc1, b_fc1, x1buf);
  fc23_kernel<<<dim3(1), 64, 0, stream>>>(x1buf, w_fc2, b_fc2, w_fc3, b_fc3,
                                          (float*)d_out);
}

// Round 5
// 1140.154 us; speedup vs baseline: 12.8783x; 1.2416x over previous
//
#include <hip/hip_runtime.h>
#include <math.h>

using half8 = __attribute__((ext_vector_type(8))) _Float16;
using f32x4 = __attribute__((ext_vector_type(4))) float;

// ---------------------------------------------------------------------------
// Coalesced weight re-tiling: w (OIHW fp32) -> Wt fp16 tiles
// [mt][ktile][g][mi][8].  ktile order: cc (ci chunks of 128) -> khkw (9) ->
// sub (cw/32).  Element (g,mi,i) of tile = w[mt*BM+mi][cc*128+sub*32+8g+i][khkw].
// ---------------------------------------------------------------------------
template<int CIN, int KC, int M_, int BM>
__global__ __launch_bounds__(256)
void transform_w(const float* __restrict__ w, _Float16* __restrict__ wt) {
  constexpr int NT = (KC / 32) * 9;
  __shared__ float lds[32 * 289];
  const int tid = threadIdx.x;
  const int s   = blockIdx.x;          // ci chunk of 32: ci0 = 32*s
  const int m0  = blockIdx.y * 32;
  const int ci0 = s * 32;
  int vlen = (CIN - ci0) * 9;          // valid floats per row chunk
  if (vlen > 288) vlen = 288;
  if (vlen < 0) vlen = 0;

  for (int e = tid; e < 32 * 288; e += 256) {
    const int mi = e / 288, o = e - mi * 288;
    float v = 0.f;
    if (o < vlen) v = w[(size_t)(m0 + mi) * (CIN * 9) + (size_t)ci0 * 9 + o];
    lds[mi * 289 + o] = v;
  }
  __syncthreads();

  const int cc  = s >> 2;
  const int sub = s & 3;
  int ns = (KC - 128 * cc) / 32; if (ns > 4) ns = 4;
  const int mt = m0 / BM;
  const int mb = m0 - mt * BM;         // m offset within BM tile
  _Float16* base = wt + (size_t)mt * NT * (BM * 32);

  for (int u = tid; u < 36 * 256; u += 256) {
    const int chunk  = u >> 8;         // 0..35
    const int within = u & 255;
    const int g = chunk & 3, khkw = chunk >> 2;
    const int mi = within >> 3, i = within & 7;
    const int kt = 36 * cc + khkw * ns + sub;
    const float v = lds[mi * 289 + (8 * g + i) * 9 + khkw];
    base[(size_t)kt * (BM * 32) + g * (BM * 8) + (mb + mi) * 8 + i] = (_Float16)v;
  }
}

// ---------------------------------------------------------------------------
// fp16 MFMA implicit-GEMM conv for 3x3 convs on 7x7 inputs (NCHW).
// Block: BM out-channels x 2 objects, 512 threads = 8 waves = 4 m-groups x 2
// objects.  A-fragments are read directly from global Wt with a REGISTER
// DOUBLE-BUFFER: ktile+1's fragments are in flight while ktile's MFMAs run
// (the Wt tile walk is linear, so one pointer increment per ktile).  Only X
// is staged in LDS (per 128-ci chunk, 2 barriers per chunk).  Row 49 of x_s
// is a zero row for padding/OOB.
// ---------------------------------------------------------------------------
template<int KC, int M_, int BM, int FN, int OHW, int PAD, typename OUT_T, typename IN_T>
__global__ __launch_bounds__(512, 4)
void conv_mfma(const _Float16* __restrict__ Wt, const IN_T* __restrict__ X,
               const float* __restrict__ bias, OUT_T* __restrict__ out,
               int outc, int co_off) {
  constexpr int NT   = (KC / 32) * 9;
  constexpr int OPOS = OHW * OHW;
  constexpr int WM   = BM / 4;
  constexpr int FR   = WM / 16;

  __shared__ alignas(16) _Float16 x_s[2][50][136];

  const int tid  = threadIdx.x;
  const int wid  = tid >> 6;
  const int lane = tid & 63;
  const int g    = lane >> 4;
  const int ln   = lane & 15;
  const int obj  = wid >> 2;
  const int wm   = (wid & 3) * WM;
  const int mt   = blockIdx.x;
  const int op   = blockIdx.y;

  if (tid < 272) x_s[tid / 136][49][tid % 136] = (_Float16)0.f;

  int ohv[FN], owv[FN];
  bool pvv[FN];
#pragma unroll
  for (int f = 0; f < FN; f++) {
    const int pos = ln + 16 * f;
    pvv[f] = pos < OPOS;
    ohv[f] = pos / OHW;
    owv[f] = pos % OHW;
  }

  f32x4 acc[FR][FN];
#pragma unroll
  for (int r = 0; r < FR; r++)
#pragma unroll
    for (int f = 0; f < FN; f++) acc[r][f] = (f32x4){0.f, 0.f, 0.f, 0.f};

  const IN_T* X0 = X + (size_t)(2 * op) * KC * 49;
  const IN_T* X1 = X + (size_t)(2 * op + 1) * KC * 49;

  // A-fragment register double-buffer: afn always holds the NEXT ktile.
  // Final iteration prefetches 16KB past this mt's tile -- in-bounds ws
  // memory, values never used.
  const _Float16* ap = Wt + (size_t)mt * NT * (BM * 32) + (g * BM + wm + ln) * 8;
  half8 afn[FR];
#pragma unroll
  for (int r = 0; r < FR; r++) afn[r] = *(const half8*)(ap + r * 128);

  for (int cbase = 0; cbase < KC; cbase += 128) {
    const int cw = (KC - cbase < 128) ? (KC - cbase) : 128;
    __syncthreads();   // all waves done reading previous x_s chunk
    for (int e = tid; e < 2 * cw * 49; e += 512) {
      const int o = e / (cw * 49);
      const int r = e - o * (cw * 49);
      const int ci = r / 49, pos = r - ci * 49;
      const float v = (float)((o ? X1 : X0)[(size_t)cbase * 49 + r]);
      x_s[o][pos][ci] = (_Float16)v;
    }
    __syncthreads();
    const int nsub = cw / 32;
    for (int khkw = 0; khkw < 9; khkw++) {
      const int kh = khkw / 3, kw = khkw - 3 * (khkw / 3);
      int boff[FN];
#pragma unroll
      for (int f = 0; f < FN; f++) {
        const int ih = ohv[f] + kh - PAD;
        const int iw = owv[f] + kw - PAD;
        bool v = pvv[f];
        if (PAD) v = v && ((unsigned)ih < 7u) && ((unsigned)iw < 7u);
        const int row = v ? (ih * 7 + iw) : 49;
        boff[f] = (obj * 50 * 136 + row * 136) * 2;
      }
      for (int sub = 0; sub < nsub; sub++) {
        half8 af[FR];
#pragma unroll
        for (int r = 0; r < FR; r++) af[r] = afn[r];     // consume prefetched
        ap += BM * 32;
#pragma unroll
        for (int r = 0; r < FR; r++)                     // issue next ktile
          afn[r] = *(const half8*)(ap + r * 128);
        const char* xb = (const char*)(&x_s[0][0][0]) + (sub * 32 + 8 * g) * 2;
#pragma unroll
        for (int f = 0; f < FN; f++) {
          const half8 bf = *(const half8*)(xb + boff[f]);
#pragma unroll
          for (int r = 0; r < FR; r++)
            acc[r][f] = __builtin_amdgcn_mfma_f32_16x16x32_f16(af[r], bf, acc[r][f], 0, 0, 0);
        }
      }
    }
  }

  // epilogue: D layout col=lane&15 (n), row=(lane>>4)*4+e (m within 16-frag)
  const int bo = 2 * op + obj;
#pragma unroll
  for (int f = 0; f < FN; f++) {
    const int pos = ln + 16 * f;
    if (pos < OPOS) {
#pragma unroll
      for (int r = 0; r < FR; r++) {
        const int mrow = wm + r * 16 + g * 4;
#pragma unroll
        for (int e = 0; e < 4; e++) {
          const int m = mt * BM + mrow + e;
          float v = acc[r][f][e] + bias[m];
          v = fmaxf(v, 0.f);
          out[((size_t)bo * outc + co_off + m) * OPOS + pos] = (OUT_T)v;
        }
      }
    }
  }
}

// ---------------------------------------------------------------------------
// fp32 implicit-GEMM conv + optional split-K partial output (glob path).
// ---------------------------------------------------------------------------
template<int M_, int CIN, int KH, int KW, int H, int W, int OH, int OW,
         int STRIDE, int PAD, int BATCH, int OUTC, int CO_OFF, bool RELU,
         int TM, int TN, int KSPLIT, bool PARTIAL>
__global__ __launch_bounds__(256)
void conv_gemm(const float* __restrict__ A,
               const float* __restrict__ X,
               const float* __restrict__ bias,
               float* __restrict__ out) {
  constexpr int K   = CIN * KH * KW;
  constexpr int N   = BATCH * OH * OW;
  constexpr int BK  = 16;
  constexpr int BM  = 16 * TM;
  constexpr int BN  = 16 * TN;
  constexpr int KCH = K / KSPLIT;

  __shared__ float a_s[BK][BM];
  __shared__ float b_s[BK][BN];

  const int t  = threadIdx.x;
  const int tx = t & 15;
  const int ty = t >> 4;
  const int n0 = blockIdx.x * BN;
  const int m0 = blockIdx.y * BM;
  const int kz = blockIdx.z;

  constexpr int AQ    = TM / 4;
  constexpr int TPR_A = 4 / AQ;
  const int am = t / TPR_A;
  const int ak = (t % TPR_A) * (4 * AQ);

  constexpr int BQ = TN / 4;
  const int bk = t & 15;
  const int bn = (t >> 4) * TN;

  float acc[TM][TN];
#pragma unroll
  for (int i = 0; i < TM; i++)
#pragma unroll
    for (int j = 0; j < TN; j++) acc[i][j] = 0.f;

  for (int k0 = kz * KCH; k0 < (kz + 1) * KCH; k0 += BK) {
    float4 av[AQ];
#pragma unroll
    for (int q = 0; q < AQ; q++) {
      av[q] = make_float4(0.f, 0.f, 0.f, 0.f);
      const int kq = k0 + ak + 4 * q;
      if ((m0 + am) < M_ && kq < K)
        av[q] = *reinterpret_cast<const float4*>(&A[(m0 + am) * K + kq]);
    }
    float bv[TN];
#pragma unroll
    for (int q = 0; q < TN; q++) bv[q] = 0.f;
    {
      const int kk = k0 + bk;
      if (kk < K) {
        const int ci = kk / (KH * KW);
        const int r  = kk - ci * (KH * KW);
        const int kh = r / KW;
        const int kw = r - kh * KW;
#pragma unroll
        for (int q = 0; q < TN; q++) {
          const int n = n0 + bn + q;
          if (n < N) {
            const int b   = n / (OH * OW);
            const int pos = n - b * (OH * OW);
            const int oh  = pos / OW;
            const int ow  = pos - oh * OW;
            const int ih  = oh * STRIDE - PAD + kh;
            const int iw  = ow * STRIDE - PAD + kw;
            if (ih >= 0 && ih < H && iw >= 0 && iw < W)
              bv[q] = X[((b * CIN + ci) * H + ih) * W + iw];
          }
        }
      }
    }
    __syncthreads();
#pragma unroll
    for (int q = 0; q < AQ; q++) {
      const int kq = ak + 4 * q;
      a_s[kq + 0][am] = av[q].x;
      a_s[kq + 1][am] = av[q].y;
      a_s[kq + 2][am] = av[q].z;
      a_s[kq + 3][am] = av[q].w;
    }
#pragma unroll
    for (int q = 0; q < BQ; q++)
      *reinterpret_cast<float4*>(&b_s[bk][bn + 4 * q]) =
          make_float4(bv[4 * q], bv[4 * q + 1], bv[4 * q + 2], bv[4 * q + 3]);
    __syncthreads();
#pragma unroll
    for (int kk2 = 0; kk2 < BK; kk2++) {
      float a[TM], b[TN];
#pragma unroll
      for (int q = 0; q < AQ; q++)
        *reinterpret_cast<float4*>(&a[4 * q]) =
            *reinterpret_cast<const float4*>(&a_s[kk2][ty * TM + 4 * q]);
#pragma unroll
      for (int q = 0; q < BQ; q++)
        *reinterpret_cast<float4*>(&b[4 * q]) =
            *reinterpret_cast<const float4*>(&b_s[kk2][tx * TN + 4 * q]);
#pragma unroll
      for (int i = 0; i < TM; i++)
#pragma unroll
        for (int j = 0; j < TN; j++)
          acc[i][j] = fmaf(a[i], b[j], acc[i][j]);
    }
  }

#pragma unroll
  for (int i = 0; i < TM; i++) {
    const int m = m0 + ty * TM + i;
    if (m < M_) {
#pragma unroll
      for (int j = 0; j < TN; j++) {
        const int n = n0 + tx * TN + j;
        if (n < N) {
          if (PARTIAL) {
            out[((size_t)kz * M_ + m) * N + n] = acc[i][j];
          } else {
            float v = acc[i][j] + bias[m];
            if (RELU) v = fmaxf(v, 0.f);
            const int b   = n / (OH * OW);
            const int pos = n - b * (OH * OW);
            out[(b * OUTC + CO_OFF + m) * (OH * OW) + pos] = v;
          }
        }
      }
    }
  }
}

// sum split-K partials + bias + relu
__global__ void reduce_bias_relu(const float* __restrict__ part,
                                 const float* __restrict__ bias,
                                 float* __restrict__ out, int MN, int N, int KS) {
  const int e = blockIdx.x * 256 + threadIdx.x;
  if (e >= MN) return;
  float s = 0.f;
  for (int k = 0; k < KS; k++) s += part[(size_t)k * MN + e];
  s += bias[e / N];
  out[e] = fmaxf(s, 0.f);
}

// ---------------------------------------------------------------------------
// sel2: x = sel1buf f32 (256,256,5,5), w (16,256,3,3), out (256,16,3,3) f32.
// One wave per (obj, co) pair: 4096 waves; lane-strided K=2304 reduction,
// 9 output positions accumulated per lane, xor-shuffle wave reduce.
// ---------------------------------------------------------------------------
__global__ __launch_bounds__(256)
void sel2_kernel(const float* __restrict__ x, const float* __restrict__ w,
                 const float* __restrict__ b, float* __restrict__ out) {
  const int wv   = (blockIdx.x * 256 + threadIdx.x) >> 6;   // 0..4095
  const int lane = threadIdx.x & 63;
  const int obj  = wv >> 4, co = wv & 15;
  float acc[9];
#pragma unroll
  for (int p = 0; p < 9; p++) acc[p] = 0.f;
  const float* xo = x + (size_t)obj * 256 * 25;
  const float* wo = w + (size_t)co * 2304;
  for (int k = lane; k < 2304; k += 64) {
    const int ci = k / 9, rr = k - 9 * ci;
    const int kh = rr / 3, kw = rr - 3 * kh;
    const float wval = wo[k];
    const float* xc = xo + ci * 25;
#pragma unroll
    for (int oh = 0; oh < 3; oh++)
#pragma unroll
      for (int ow = 0; ow < 3; ow++)
        acc[oh * 3 + ow] = fmaf(xc[(oh + kh) * 5 + (ow + kw)], wval, acc[oh * 3 + ow]);
  }
  const float bv = b[co];
#pragma unroll
  for (int p = 0; p < 9; p++) {
    float v = acc[p];
#pragma unroll
    for (int off = 32; off; off >>= 1) v += __shfl_xor(v, off);
    if (lane == 0) out[(size_t)wv * 9 + p] = fmaxf(v + bv, 0.f);
  }
}

// ---------------------------------------------------------------------------
// sin buffer (256, 544, 7, 7) fp16: ch 0..3 = bb, 260..515 = glob, 516..543=0.
// (ch 4..259 written by obj2 conv.)
// ---------------------------------------------------------------------------
__global__ void prep_sin(const float* __restrict__ bbox,
                         const float* __restrict__ glob,
                         _Float16* __restrict__ sinb) {
  const int b = blockIdx.x;
  const float x0 = bbox[b * 4 + 0], y0 = bbox[b * 4 + 1];
  const float x1 = bbox[b * 4 + 2], y1 = bbox[b * 4 + 3];
  const float bbv[4] = {x0 / 1280.f, y0 / 720.f,
                        logf(1280.f / (x1 - x0)), logf(720.f / (y1 - y0))};
  _Float16* base = sinb + (size_t)b * 544 * 49;
  for (int e = threadIdx.x; e < 4 * 49; e += blockDim.x)
    base[e] = (_Float16)bbv[e / 49];
  for (int e = threadIdx.x; e < 256 * 49; e += blockDim.x)
    base[260 * 49 + e] = (_Float16)glob[e];
  for (int e = threadIdx.x; e < 28 * 49; e += blockDim.x)
    base[516 * 49 + e] = (_Float16)0.f;
}

// ---------------------------------------------------------------------------
__global__ void score_top5(const float* __restrict__ sel2,
                           const float* __restrict__ w3,
                           const float* __restrict__ b3,
                           int* __restrict__ idx_out) {
  __shared__ float w_s[144];
  __shared__ float s_s[256];
  const int t = threadIdx.x;
  if (t < 144) w_s[t] = w3[t];
  __syncthreads();
  float acc = b3[0];
  const float* p = sel2 + t * 144;
  for (int k = 0; k < 144; k++) acc += p[k] * w_s[k];
  s_s[t] = acc;
  __syncthreads();
  if (t == 0) {
    for (int i = 0; i < 5; i++) {
      float best = -1e30f;
      int bi = 0;
      for (int j = 0; j < 256; j++)
        if (s_s[j] > best) { best = s_s[j]; bi = j; }
      idx_out[i] = bi;
      s_s[bi] = -1e30f;
    }
  }
}

__global__ void pool_kernel(const _Float16* __restrict__ sinb,
                            const float* __restrict__ glob,
                            const int* __restrict__ idx,
                            float* __restrict__ objsel,
                            float* __restrict__ g) {
  const int blk = blockIdx.x;
  const int t = threadIdx.x;
  if (blk < 5) {
    const int b = idx[blk];
    const _Float16* base = sinb + (size_t)b * 544 * 49;
    for (int c = t; c < 260; c += blockDim.x) {
      float s = 0.f;
      for (int p = 0; p < 49; p++) s += (float)base[c * 49 + p];
      objsel[blk * 260 + c] = s * (1.f / 245.f);
    }
  } else {
    if (t < 256) {
      float s = 0.f;
      const float* p = glob + t * 49;
      for (int q = 0; q < 49; q++) s += p[q];
      g[t] = s * (1.f / 49.f);
    }
  }
}

__global__ void fc1_kernel(const float* __restrict__ objsel,
                           const float* __restrict__ g,
                           const float* __restrict__ w,
                           const float* __restrict__ b,
                           float* __restrict__ x1) {
  const int co = threadIdx.x;
  float acc[5];
#pragma unroll
  for (int i = 0; i < 5; i++) acc[i] = b[co];
  for (int k = 0; k < 260; k++) {
    const float wv = w[k * 256 + co];
#pragma unroll
    for (int i = 0; i < 5; i++) acc[i] = fmaf(objsel[i * 260 + k], wv, acc[i]);
  }
  for (int k = 260; k < 516; k++) {
    const float wv = w[k * 256 + co];
    const float gv = g[k - 260];
#pragma unroll
    for (int i = 0; i < 5; i++) acc[i] = fmaf(gv, wv, acc[i]);
  }
#pragma unroll
  for (int i = 0; i < 5; i++) x1[i * 256 + co] = fmaxf(acc[i], 0.f);
}

__global__ void fc23_kernel(const float* __restrict__ x1,
                            const float* __restrict__ w2,
                            const float* __restrict__ b2,
                            const float* __restrict__ w3,
                            const float* __restrict__ b3,
                            float* __restrict__ out) {
  __shared__ float x2[64];
  const int j = threadIdx.x;
  float acc = b2[j];
  for (int k = 0; k < 1280; k++) acc = fmaf(x1[k], w2[k * 64 + j], acc);
  x2[j] = fmaxf(acc, 0.f);
  __syncthreads();
  if (j < 4) {
    float a = b3[j];
    for (int k = 0; k < 64; k++) a = fmaf(x2[k], w3[k * 4 + j], a);
    out[j] = a;
  }
}

// ---------------------------------------------------------------------------
extern "C" void kernel_launch(void* const* d_in, const int* in_sizes, int n_in,
                              void* d_out, int out_size, void* d_ws, size_t ws_size,
                              hipStream_t stream) {
  (void)in_sizes; (void)n_in; (void)out_size; (void)ws_size;
  const float* glob_feature = (const float*)d_in[0];
  const float* roi          = (const float*)d_in[1];
  const float* bbox         = (const float*)d_in[2];
  const float* w_glob1      = (const float*)d_in[3];
  const float* b_glob1      = (const float*)d_in[4];
  const float* w_glob2      = (const float*)d_in[5];
  const float* b_glob2      = (const float*)d_in[6];
  const float* w_obj1       = (const float*)d_in[7];
  const float* b_obj1       = (const float*)d_in[8];
  const float* w_obj2       = (const float*)d_in[9];
  const float* b_obj2       = (const float*)d_in[10];
  const float* w_sel1       = (const float*)d_in[11];
  const float* b_sel1       = (const float*)d_in[12];
  const float* w_sel2       = (const float*)d_in[13];
  const float* b_sel2       = (const float*)d_in[14];
  const float* w_sel3       = (const float*)d_in[15];
  const float* b_sel3       = (const float*)d_in[16];
  const float* w_fc1        = (const float*)d_in[17];
  const float* b_fc1        = (const float*)d_in[18];
  const float* w_fc2        = (const float*)d_in[19];
  const float* b_fc2        = (const float*)d_in[20];
  const float* w_fc3        = (const float*)d_in[21];
  const float* b_fc3        = (const float*)d_in[22];

  float* ws = (float*)d_ws;
  // Region A (f32 [0, 9437184)): W''_obj1 during obj1; afterwards reused for
  // sinbuf / W''_obj2 / W''_sel1 / sel1buf / glob scratch (obj1 runs first).
  _Float16* wbuf1   = (_Float16*)(ws);                 // 18,874,368 halves
  _Float16* sinbuf  = (_Float16*)(ws);                 // 6,823,936 halves (alias, post-obj1)
  _Float16* wbuf2   = (_Float16*)(ws + 3412000);       // 2,359,296 halves
  _Float16* wbufs1  = (_Float16*)(ws + 4591648);       // 1,253,376 halves
  float*    sel1buf = ws + 5218336;                    // 1,638,400 f32
  float*    glob1buf= ws + 6856736;                    // 100,352 f32
  float*    part1   = ws + 6957088;                    // 1,605,632 f32 (16-way)
  float*    part2   = ws + 8562720;                    // 200,704 f32
  float*    sel2buf = ws + 8763424;                    // 36,864 f32
  _Float16* obj1buf = (_Float16*)(ws + 9437184);       // 12,845,056 halves
  float*    globbuf = ws + 15859712;                   // 12,544 f32
  int*      idxbuf  = (int*)(ws + 15872256);           // 8
  float*    objsel  = ws + 15872264;                   // 1,300
  float*    gbuf    = ws + 15873564;                   // 256
  float*    x1buf   = ws + 15873820;                   // 1,280
  // total ~63.5 MB

  // --- obj1: transform weights (into region A), then MFMA conv ---
  transform_w<2048, 2048, 1024, 256><<<dim3(64, 32), 256, 0, stream>>>(w_obj1, wbuf1);
  conv_mfma<2048, 1024, 256, 4, 7, 1, _Float16, float>
      <<<dim3(4, 128), 512, 0, stream>>>(wbuf1, roi, b_obj1, obj1buf, 1024, 0);

  // --- region A now free: obj2/sel1 weight transforms + glob path ---
  transform_w<1024, 1024, 256, 128><<<dim3(32, 8), 256, 0, stream>>>(w_obj2, wbuf2);
  transform_w<516, 544, 256, 128><<<dim3(17, 8), 256, 0, stream>>>(w_sel1, wbufs1);

  conv_gemm<512, 1024, 4, 4, 28, 28, 14, 14, 2, 1, 1, 512, 0, true, 4, 4, 16, true>
      <<<dim3(4, 8, 16), 256, 0, stream>>>(w_glob1, glob_feature, b_glob1, part1);
  reduce_bias_relu<<<dim3(392), 256, 0, stream>>>(part1, b_glob1, glob1buf, 100352, 196, 16);
  conv_gemm<256, 512, 4, 4, 14, 14, 7, 7, 2, 1, 1, 256, 0, true, 4, 4, 16, true>
      <<<dim3(1, 4, 16), 256, 0, stream>>>(w_glob2, glob1buf, b_glob2, part2);
  reduce_bias_relu<<<dim3(49), 256, 0, stream>>>(part2, b_glob2, globbuf, 12544, 49, 16);

  prep_sin<<<dim3(256), 256, 0, stream>>>(bbox, globbuf, sinbuf);

  // --- obj2 (writes sin ch 4..259), sel branch ---
  conv_mfma<1024, 256, 128, 4, 7, 1, _Float16, _Float16>
      <<<dim3(2, 128), 512, 0, stream>>>(wbuf2, obj1buf, b_obj2, sinbuf, 544, 4);
  conv_mfma<544, 256, 128, 2, 5, 0, float, _Float16>
      <<<dim3(2, 128), 512, 0, stream>>>(wbufs1, sinbuf, b_sel1, sel1buf, 256, 0);
  sel2_kernel<<<dim3(1024), 256, 0, stream>>>(sel1buf, w_sel2, b_sel2, sel2buf);
  score_top5<<<dim3(1), 256, 0, stream>>>(sel2buf, w_sel3, b_sel3, idxbuf);

  // --- pooling + FC head ---
  pool_kernel<<<dim3(6), 256, 0, stream>>>(sinbuf, globbuf, idxbuf, objsel, gbuf);
  fc1_kernel<<<dim3(1), 256, 0, stream>>>(objsel, gbuf, w_fc1, b_fc1, x1buf);
  fc23_kernel<<<dim3(1), 64, 0, stream>>>(x1buf, w_fc2, b_fc2, w_fc3, b_fc3,
                                          (float*)d_out);
}